// Round 2
// baseline (44.673 us; speedup 1.0000x reference)
//
#include <hip/hip_runtime.h>
#include <hip/hip_bf16.h>

#define BB 4
#define CC 512    // C_CTX
#define TDIM 512  // T
#define HH 128
#define TT 8      // t-rows per block in main kernel

// ---------------- prep: key/query/value projections (f32 to ws) -------------
__global__ __launch_bounds__(128) void prep_kernel(
    const float* __restrict__ ctx_x, const float* __restrict__ ctx_y,
    const float* __restrict__ tgt_x,
    const float* __restrict__ W_in, const float* __restrict__ b_in,
    const float* __restrict__ W_ctx, const float* __restrict__ b_ctx,
    float* __restrict__ key, float* __restrict__ query, float* __restrict__ value)
{
    int row = blockIdx.x;     // 0 .. BB*512-1  (b*512 + r)
    int h   = threadIdx.x;    // 0 .. 127

    float4 cx = ((const float4*)ctx_x)[row];   // x0..x2 used
    float2 cy = ((const float2*)ctx_y)[row];
    float4 tx = ((const float4*)tgt_x)[row];

    float wi0 = W_in[0*HH+h], wi1 = W_in[1*HH+h], wi2 = W_in[2*HH+h];
    float wi3 = W_in[3*HH+h], wi4 = W_in[4*HH+h];
    float wc0 = W_ctx[0*HH+h], wc1 = W_ctx[1*HH+h], wc2 = W_ctx[2*HH+h];
    float bi  = b_in[h], bc = b_ctx[h];

    value[row*HH+h] = fmaf(cx.x,wi0, fmaf(cx.y,wi1, fmaf(cx.z,wi2, fmaf(cy.x,wi3, fmaf(cy.y,wi4, bi)))));
    key  [row*HH+h] = fmaf(cx.x,wc0, fmaf(cx.y,wc1, fmaf(cx.z,wc2, bc)));
    query[row*HH+h] = fmaf(tx.x,wc0, fmaf(tx.y,wc1, fmaf(tx.z,wc2, bc)));
}

// ---------------- main: L1 scores + softmax + PV + out-projection ------------
__global__ __launch_bounds__(256) void main_kernel(
    const float* __restrict__ key, const float* __restrict__ query,
    const float* __restrict__ value,
    const float* __restrict__ W_tgt, const float* __restrict__ b_tgt,
    float* __restrict__ out)
{
    const int b   = blockIdx.x / (TDIM/TT);
    const int tb  = blockIdx.x % (TDIM/TT);
    const int t0  = tb * TT;
    const int tid = threadIdx.x;

    __shared__ float q[TT][HH];           // 4 KB
    __shared__ float s[TT][CC];           // 16 KB raw scores
    __shared__ float wT[CC][TT];          // 16 KB softmax weights, transposed
    __shared__ float partial[2][TT][HH];  // 8 KB
    __shared__ float rep[TT][HH];         // 4 KB

    // --- load query tile into LDS ---
    for (int i = tid; i < TT*HH; i += 256) {
        int t = i >> 7, h = i & 127;
        q[t][h] = query[(b*TDIM + t0 + t)*HH + h];
    }
    __syncthreads();

    // --- scores: each thread owns 2 context rows ---
    for (int ci = 0; ci < 2; ++ci) {
        int c = tid + ci*256;
        const float4* krow = (const float4*)&key[(b*CC + c)*HH];
        float acc[TT];
        #pragma unroll
        for (int t = 0; t < TT; ++t) acc[t] = 0.f;
        #pragma unroll
        for (int hc = 0; hc < 8; ++hc) {          // chunks of 16 h
            float4 k0 = krow[hc*4+0], k1 = krow[hc*4+1];
            float4 k2 = krow[hc*4+2], k3 = krow[hc*4+3];
            #pragma unroll
            for (int t = 0; t < TT; ++t) {
                const float4* qp = (const float4*)&q[t][hc*16];
                float4 q0 = qp[0], q1 = qp[1], q2 = qp[2], q3 = qp[3];
                float a = fabsf(k0.x-q0.x)+fabsf(k0.y-q0.y)+fabsf(k0.z-q0.z)+fabsf(k0.w-q0.w)
                        + fabsf(k1.x-q1.x)+fabsf(k1.y-q1.y)+fabsf(k1.z-q1.z)+fabsf(k1.w-q1.w)
                        + fabsf(k2.x-q2.x)+fabsf(k2.y-q2.y)+fabsf(k2.z-q2.z)+fabsf(k2.w-q2.w)
                        + fabsf(k3.x-q3.x)+fabsf(k3.y-q3.y)+fabsf(k3.z-q3.z)+fabsf(k3.w-q3.w);
                acc[t] += a;
            }
        }
        #pragma unroll
        for (int t = 0; t < TT; ++t) s[t][c] = -0.5f * acc[t];
    }
    __syncthreads();

    // --- softmax: wave w owns t = 2w, 2w+1 (full 64-lane reduce) ---
    {
        int wave = tid >> 6;
        int lane = tid & 63;
        for (int tw = 0; tw < 2; ++tw) {
            int t = wave*2 + tw;
            float m = -1e30f;
            #pragma unroll
            for (int i = 0; i < 8; ++i) m = fmaxf(m, s[t][lane + 64*i]);
            #pragma unroll
            for (int msk = 32; msk; msk >>= 1) m = fmaxf(m, __shfl_xor(m, msk));
            float e[8];
            float sum = 0.f;
            #pragma unroll
            for (int i = 0; i < 8; ++i) { e[i] = __expf(s[t][lane + 64*i] - m); sum += e[i]; }
            #pragma unroll
            for (int msk = 32; msk; msk >>= 1) sum += __shfl_xor(sum, msk);
            float inv = 1.f / sum;
            #pragma unroll
            for (int i = 0; i < 8; ++i) wT[lane + 64*i][t] = e[i] * inv;
        }
    }
    __syncthreads();

    // --- rep[t][h] = sum_c w[t][c] * value[c][h]; split c-range in 2 groups ---
    {
        int g = tid >> 7;        // 0..1
        int h = tid & 127;
        float racc[TT];
        #pragma unroll
        for (int t = 0; t < TT; ++t) racc[t] = 0.f;
        for (int c = g*256; c < g*256 + 256; ++c) {
            float v = value[(b*CC + c)*HH + h];
            const float4* wp = (const float4*)&wT[c][0];
            float4 w0 = wp[0], w1 = wp[1];
            racc[0] = fmaf(w0.x, v, racc[0]);
            racc[1] = fmaf(w0.y, v, racc[1]);
            racc[2] = fmaf(w0.z, v, racc[2]);
            racc[3] = fmaf(w0.w, v, racc[3]);
            racc[4] = fmaf(w1.x, v, racc[4]);
            racc[5] = fmaf(w1.y, v, racc[5]);
            racc[6] = fmaf(w1.z, v, racc[6]);
            racc[7] = fmaf(w1.w, v, racc[7]);
        }
        #pragma unroll
        for (int t = 0; t < TT; ++t) partial[g][t][h] = racc[t];
    }
    __syncthreads();
    for (int i = tid; i < TT*HH; i += 256) {
        int t = i >> 7, h = i & 127;
        rep[t][h] = partial[0][t][h] + partial[1][t][h];
    }
    __syncthreads();

    // --- out[t][h] = rep[t] @ W_tgt[:,h] + b_tgt[h]; thread (g,h) does 4 t ---
    {
        int g = tid >> 7;
        int h = tid & 127;
        float bt = b_tgt[h];
        float oacc[4];
        #pragma unroll
        for (int i = 0; i < 4; ++i) oacc[i] = bt;
        for (int k = 0; k < HH; ++k) {
            float wt = W_tgt[k*HH + h];
            #pragma unroll
            for (int i = 0; i < 4; ++i)
                oacc[i] = fmaf(rep[g*4 + i][k], wt, oacc[i]);
        }
        #pragma unroll
        for (int i = 0; i < 4; ++i) {
            int t = g*4 + i;
            out[(b*TDIM + t0 + t)*HH + h] = oacc[i];
        }
    }
}

extern "C" void kernel_launch(void* const* d_in, const int* in_sizes, int n_in,
                              void* d_out, int out_size, void* d_ws, size_t ws_size,
                              hipStream_t stream) {
    const float* ctx_x = (const float*)d_in[0];
    const float* ctx_y = (const float*)d_in[1];
    const float* tgt_x = (const float*)d_in[2];
    const float* W_in  = (const float*)d_in[3];
    const float* b_in  = (const float*)d_in[4];
    const float* W_ctx = (const float*)d_in[5];
    const float* b_ctx = (const float*)d_in[6];
    const float* W_tgt = (const float*)d_in[7];
    const float* b_tgt = (const float*)d_in[8];

    float* ws    = (float*)d_ws;
    float* key   = ws;
    float* query = ws + BB*CC*HH;
    float* value = ws + 2*BB*CC*HH;

    prep_kernel<<<BB*CC, 128, 0, stream>>>(ctx_x, ctx_y, tgt_x,
                                           W_in, b_in, W_ctx, b_ctx,
                                           key, query, value);
    main_kernel<<<BB*(TDIM/TT), 256, 0, stream>>>(key, query, value,
                                                  W_tgt, b_tgt, (float*)d_out);
}